// Round 4
// baseline (3760.835 us; speedup 1.0000x reference)
//
#include <hip/hip_runtime.h>

// ---------------- problem constants ----------------
#define B_  64
#define S_  512
#define L_  16
#define WD_ 200
#define CD_ 30
#define FN_ 4
#define KW_ 3
#define H_  256
#define T_  17
#define D_  320   // WD + CD*FN

typedef unsigned short ushort_t;
typedef __attribute__((ext_vector_type(8))) short v8s;   // bf16x8 MFMA frag
typedef __attribute__((ext_vector_type(4))) float v4f;   // fp32x4 MFMA acc
typedef __attribute__((ext_vector_type(4))) float f4;
typedef __attribute__((ext_vector_type(4))) unsigned int ui4;
typedef __attribute__((ext_vector_type(4))) unsigned short us4;

__device__ __forceinline__ unsigned short f2bf(float f) {
  union { float f; unsigned int i; } v; v.f = f;
  unsigned int r = v.i + 0x7fffu + ((v.i >> 16) & 1u);   // RNE
  return (unsigned short)(r >> 16);
}

// ---------------- K1: word emb (f32->bf16) + char CNN + maxpool -> z [B*S, 320] bf16 ----------------
__global__ __launch_bounds__(64) void k_embed(
    const int* __restrict__ tok, const int* __restrict__ ctok,
    const float* __restrict__ wemb, const float* __restrict__ cemb,
    const float* __restrict__ cw, const float* __restrict__ cb,
    ushort_t* __restrict__ z)
{
  int w = blockIdx.x;           // word index = b*S + s
  int l = threadIdx.x;
  __shared__ float ce[L_][32];  // char embeddings fp32
  if (l < L_) {
    int cid = ctok[w * L_ + l];
    const float* row = cemb + (size_t)cid * CD_;
    #pragma unroll
    for (int j = 0; j < CD_; ++j) ce[l][j] = row[j];
  }
  // word embedding: 200 f32 -> 200 bf16 (50 lanes x 4)
  int t = tok[w];
  const f4* src = (const f4*)(wemb + (size_t)t * WD_);   // t*200*4B, 16B-aligned
  if (l < 50) {
    f4 v = src[l];
    us4 o; o[0]=f2bf(v[0]); o[1]=f2bf(v[1]); o[2]=f2bf(v[2]); o[3]=f2bf(v[3]);
    *(us4*)(z + (size_t)w * D_ + l*4) = o;
  }
  __syncthreads();
  // grouped conv (groups=CD, FN filters each, KW=3, VALID) + maxpool
  for (int oc = l; oc < CD_ * FN_; oc += 64) {
    int c = oc >> 2;   // group = oc / FN
    float w0 = cw[oc*3+0], w1 = cw[oc*3+1], w2 = cw[oc*3+2];
    float mx = -3e30f;
    #pragma unroll
    for (int p = 0; p < L_ - KW_ + 1; ++p) {
      float s = ce[p][c]*w0 + ce[p+1][c]*w1 + ce[p+2][c]*w2;
      mx = fmaxf(mx, s);
    }
    z[(size_t)w * D_ + WD_ + oc] = f2bf(mx + cb[oc]);
  }
}

// ---------------- K2: gx[dir][s][b][1024] = z @ W_ih^T  (bf16 MFMA; W is f32, cvt on stage) ----------
__global__ __launch_bounds__(256) void k_gemm_gx(
    const ushort_t* __restrict__ z, const float* __restrict__ wf,
    const float* __restrict__ wb, ushort_t* __restrict__ gx)
{
  __shared__ ushort_t As[128 * 40];   // pitch 40 to break bank aliasing
  __shared__ ushort_t Bs[64 * 40];
  int m0 = blockIdx.x * 128;
  int n0g = blockIdx.y * 64;          // 0..2047 across both directions
  int dir = n0g >> 10;
  int ncol0 = n0g & 1023;
  const float* W = dir ? wb : wf;
  int tid = threadIdx.x;
  int wv = tid >> 6, l = tid & 63;
  int lm = l & 15, lq = l >> 4;
  v4f acc[2][4];
  #pragma unroll
  for (int i = 0; i < 2; i++)
    #pragma unroll
    for (int j = 0; j < 4; j++) acc[i][j] = (v4f)0.f;

  for (int kc = 0; kc < 10; ++kc) {
    int k0 = kc * 32;
    // stage A (bf16 z): 128 rows x 32 cols = 512 x 16B -> 2 per thread
    #pragma unroll
    for (int rep = 0; rep < 2; ++rep) {
      int idx = rep * 256 + tid;
      int row = idx >> 2, q = idx & 3;
      *(ui4*)(As + row*40 + q*8) =
          *(const ui4*)(z + (size_t)(m0 + row)*D_ + k0 + q*8);
    }
    { // stage B (f32 W -> bf16): 64 rows x 32 cols; thread: row=tid>>2, 8 elems
      int row = tid >> 2, q = tid & 3;
      const float* src = W + (size_t)(ncol0 + row)*D_ + k0 + q*8;
      f4 a = *(const f4*)src, b2 = *(const f4*)(src + 4);
      us4 o0, o1;
      o0[0]=f2bf(a[0]); o0[1]=f2bf(a[1]); o0[2]=f2bf(a[2]); o0[3]=f2bf(a[3]);
      o1[0]=f2bf(b2[0]); o1[1]=f2bf(b2[1]); o1[2]=f2bf(b2[2]); o1[3]=f2bf(b2[3]);
      *(us4*)(Bs + row*40 + q*8) = o0;
      *(us4*)(Bs + row*40 + q*8 + 4) = o1;
    }
    __syncthreads();
    v8s a0 = *(const v8s*)(As + (wv*32 + lm)*40 + lq*8);
    v8s a1 = *(const v8s*)(As + (wv*32 + 16 + lm)*40 + lq*8);
    #pragma unroll
    for (int nt = 0; nt < 4; ++nt) {
      v8s b = *(const v8s*)(Bs + (nt*16 + lm)*40 + lq*8);
      acc[0][nt] = __builtin_amdgcn_mfma_f32_16x16x32_bf16(a0, b, acc[0][nt], 0, 0, 0);
      acc[1][nt] = __builtin_amdgcn_mfma_f32_16x16x32_bf16(a1, b, acc[1][nt], 0, 0, 0);
    }
    __syncthreads();
  }
  // epilogue: C layout col=l&15, row=(l>>4)*4+r ; m = b*S + s
  #pragma unroll
  for (int mt = 0; mt < 2; mt++)
    #pragma unroll
    for (int nt = 0; nt < 4; nt++)
      #pragma unroll
      for (int r = 0; r < 4; r++) {
        int m = m0 + wv*32 + mt*16 + lq*4 + r;
        int col = ncol0 + nt*16 + lm;
        int b = m >> 9, s = m & 511;
        gx[(((size_t)dir*512 + s)*64 + b)*1024 + col] = f2bf(acc[mt][nt][r]);
      }
}

// ---------------- K3: persistent-weight bidirectional LSTM ----------------
// 32 blocks: dir(2) x batch-group(4, 16 each) x col-block(4, 64 H-units each).
// W_hh slice (f32 -> bf16) lives in registers (128 VGPR/wave). Col-blocks of a
// cluster exchange h each step via global double buffer + device-scope counter.
__global__ __launch_bounds__(256) void k_lstm(
    const ushort_t* __restrict__ gx,
    const float* __restrict__ whhf, const float* __restrict__ whhb,
    const float* __restrict__ bf_, const float* __restrict__ bb_,
    ushort_t* __restrict__ hbuf, ushort_t* __restrict__ hs,
    int* __restrict__ cnt)
{
  int bid = blockIdx.x;
  int dir = bid >> 4, grp = (bid >> 2) & 3, cb = bid & 3;
  int tid = threadIdx.x, w = tid >> 6, l = tid & 63;
  int lm = l & 15, lq = l >> 4;
  int u0 = cb * 64, b0 = grp * 16;
  const float* W = dir ? whhb : whhf;
  const float* bias = dir ? bb_ : bf_;
  int Rb = w * 256 + u0;          // wave w handles gate w rows [Rb, Rb+64)
  // persistent weight fragments: 4 n-tiles x 8 k-chunks (f32 load -> bf16 pack)
  v8s wfr[4][8];
  #pragma unroll
  for (int nt = 0; nt < 4; nt++)
    #pragma unroll
    for (int kc = 0; kc < 8; kc++) {
      const float* src = W + (size_t)(Rb + nt*16 + lm)*256 + kc*32 + lq*8;
      f4 a = *(const f4*)src, b2 = *(const f4*)(src + 4);
      v8s f;
      f[0]=(short)f2bf(a[0]); f[1]=(short)f2bf(a[1]); f[2]=(short)f2bf(a[2]); f[3]=(short)f2bf(a[3]);
      f[4]=(short)f2bf(b2[0]); f[5]=(short)f2bf(b2[1]); f[6]=(short)f2bf(b2[2]); f[7]=(short)f2bf(b2[3]);
      wfr[nt][kc] = f;
    }
  float bv[4];
  #pragma unroll
  for (int nt = 0; nt < 4; nt++) bv[nt] = bias[Rb + nt*16 + lm];

  float c[4] = {0.f, 0.f, 0.f, 0.f};     // cell state, fp32 in regs
  int b_l = tid >> 4, u_l = (tid & 15) * 4;
  __shared__ float gb[4][16][64];        // activated gates [gate][batch][unit]
  int cid = dir * 4 + grp;
  int* cp = cnt + cid;
  ushort_t* hbb = hbuf + (size_t)cid * 2 * (16 * 256);

  union { unsigned int u; float f; } bc;
  for (int n = 0; n < 512; ++n) {
    int t = dir ? (511 - n) : n;
    // gx loads for this step (independent of h) — issue before the wait
    const ushort_t* gxp = gx + ((size_t)dir*512 + t) * 64 * 1024;
    float gxr[4][4];
    #pragma unroll
    for (int nt = 0; nt < 4; nt++)
      #pragma unroll
      for (int r = 0; r < 4; r++) {
        bc.u = (unsigned int)gxp[(size_t)(b0 + lq*4 + r)*1024 + w*256 + u0 + nt*16 + lm] << 16;
        gxr[nt][r] = bc.f;
      }

    if (n > 0) {
      if (tid == 0) {
        int target = 4 * n;
        for (int it = 0; it < (1 << 22); ++it) {
          if (__hip_atomic_load(cp, __ATOMIC_RELAXED, __HIP_MEMORY_SCOPE_AGENT) >= target) break;
          __builtin_amdgcn_s_sleep(2);
        }
      }
      __syncthreads();
      __builtin_amdgcn_fence(__ATOMIC_ACQUIRE, "agent");   // make peers' h stores visible
    }
    // A frags = h_{t-1} [16 x 256] bf16 from read-parity buffer
    const ushort_t* hrp = hbb + (size_t)((n & 1) ^ 1) * (16 * 256);
    v4f acc[4];
    #pragma unroll
    for (int nt = 0; nt < 4; nt++) acc[nt] = (v4f)0.f;
    #pragma unroll
    for (int kc = 0; kc < 8; kc++) {
      v8s af = *(const v8s*)(hrp + lm*256 + kc*32 + lq*8);
      #pragma unroll
      for (int nt = 0; nt < 4; nt++)
        acc[nt] = __builtin_amdgcn_mfma_f32_16x16x32_bf16(af, wfr[nt][kc], acc[nt], 0, 0, 0);
    }
    // gates + activation -> LDS  (wave w: 0=i sigm, 1=f sigm, 2=g tanh, 3=o sigm)
    #pragma unroll
    for (int nt = 0; nt < 4; nt++)
      #pragma unroll
      for (int r = 0; r < 4; r++) {
        float g = acc[nt][r] + gxr[nt][r] + bv[nt];
        float a = (w == 2) ? tanhf(g) : (1.f / (1.f + expf(-g)));
        gb[w][lq*4 + r][nt*16 + lm] = a;
      }
    __syncthreads();
    // combine: each thread owns (b_l, units u_l..u_l+3); c stays fp32 in regs
    f4 iv = *(const f4*)&gb[0][b_l][u_l];
    f4 fv = *(const f4*)&gb[1][b_l][u_l];
    f4 gv = *(const f4*)&gb[2][b_l][u_l];
    f4 ov = *(const f4*)&gb[3][b_l][u_l];
    us4 hp;
    #pragma unroll
    for (int j = 0; j < 4; j++) {
      c[j] = fv[j] * c[j] + iv[j] * gv[j];
      float h = ov[j] * tanhf(c[j]);
      hp[j] = f2bf(h);
    }
    ushort_t* hwp = hbb + (size_t)(n & 1) * (16 * 256);
    *(us4*)(hwp + (size_t)b_l*256 + u0 + u_l) = hp;
    *(us4*)(hs + (((size_t)dir*512 + t)*64 + (b0 + b_l))*256 + u0 + u_l) = hp;
    __syncthreads();   // all waves' stores issued before the release-add
    if (tid == 0)
      __hip_atomic_fetch_add(cp, 1, __ATOMIC_RELEASE, __HIP_MEMORY_SCOPE_AGENT);
  }
}

// ---------------- K4: emissions[b][s][17] = [h_f, h_b] @ cls_w^T + cls_b (fp32) ----------------
__global__ __launch_bounds__(256) void k_emis(
    const ushort_t* __restrict__ hs, const float* __restrict__ clsw,
    const float* __restrict__ clsb, float* __restrict__ emis)
{
  int tid = threadIdx.x;
  if (tid >= 255) return;                 // 15 words x 17 targets per block
  int wi = blockIdx.x * 15 + tid / 17;
  int tau = tid % 17;
  if (wi >= B_ * S_) return;
  int b = wi >> 9, s = wi & 511;
  const ushort_t* hf  = hs + ((size_t)s*64 + b) * 256;
  const ushort_t* hbk = hs + (((size_t)512 + s)*64 + b) * 256;
  const float* cwf = clsw + (size_t)tau * 512;
  const float* cwb = cwf + 256;
  union { unsigned int u; float f; } bc;
  float acc = clsb[tau];
  for (int k = 0; k < 256; k += 4) {
    us4 h4 = *(const us4*)(hf + k); f4 w4 = *(const f4*)(cwf + k);
    #pragma unroll
    for (int j = 0; j < 4; j++) { bc.u = (unsigned int)h4[j] << 16; acc += bc.f * w4[j]; }
  }
  for (int k = 0; k < 256; k += 4) {
    us4 h4 = *(const us4*)(hbk + k); f4 w4 = *(const f4*)(cwb + k);
    #pragma unroll
    for (int j = 0; j < 4; j++) { bc.u = (unsigned int)h4[j] << 16; acc += bc.f * w4[j]; }
  }
  emis[(size_t)wi * 17 + tau] = acc;
}

// ---------------- K5/K6: CRF loss forward (blocks 0..15) + Viterbi (blocks 16..31) -------------
// One wave per batch element; lane tau (<17) holds alpha[tau] and trans column tau. All fp32.
__global__ __launch_bounds__(256) void k_crf(
    const float* __restrict__ emis, const int* __restrict__ labels,
    const int* __restrict__ mask, const float* __restrict__ startt,
    const float* __restrict__ endt, const float* __restrict__ trans,
    float* __restrict__ lossp, float* __restrict__ outp)
{
  __shared__ unsigned char bps[4][511][17];
  int blk = blockIdx.x;
  int tid = threadIdx.x, wv = tid >> 6, l = tid & 63;
  bool isv = blk >= 16;
  int b = (blk & 15) * 4 + wv;
  int tauc = (l < 17) ? l : 0;
  float tc[17];
  #pragma unroll
  for (int i = 0; i < 17; i++) tc[i] = trans[i*17 + tauc];
  const float* eb = emis + (size_t)b * 512 * 17;
  float alpha = startt[tauc] + eb[tauc];
  if (l >= 17) alpha = -3e30f;

  if (!isv) {
    // ---- log-partition (forward algorithm) ----
    for (int t = 1; t < 512; t++) {
      float e = (l < 17) ? eb[t*17 + l] : 0.f;
      int mt = mask[b*512 + t];
      float arr[17]; float mx = -3e30f;
      #pragma unroll
      for (int i = 0; i < 17; i++) {
        float av = __shfl(alpha, i);
        arr[i] = av + tc[i];
        mx = fmaxf(mx, arr[i]);
      }
      float ss = 0.f;
      #pragma unroll
      for (int i = 0; i < 17; i++) ss += expf(arr[i] - mx);
      float nxt = mx + logf(ss) + e;
      if (mt > 0 && l < 17) alpha = nxt;
    }
    float a2 = (l < 17) ? (alpha + endt[l]) : -3e30f;
    float mx = a2;
    #pragma unroll
    for (int o = 32; o > 0; o >>= 1) mx = fmaxf(mx, __shfl_xor(mx, o));
    float ss = (l < 17) ? expf(a2 - mx) : 0.f;
    #pragma unroll
    for (int o = 32; o > 0; o >>= 1) ss += __shfl_xor(ss, o);
    float denom = mx + logf(ss);
    // ---- gold path score ----
    float ns = 0.f; int msum = 0;
    for (int t = l; t < 512; t += 64) {
      int tg = labels[b*512 + t];
      int mt = mask[b*512 + t];
      msum += (mt > 0);
      if (mt > 0) {
        ns += eb[t*17 + tg];
        if (t > 0) ns += trans[labels[b*512 + t - 1]*17 + tg];
      }
    }
    #pragma unroll
    for (int o = 32; o > 0; o >>= 1) { ns += __shfl_xor(ns, o); msum += __shfl_xor(msum, o); }
    if (l == 0) {
      int lidx = msum - 1;
      float num = ns + startt[labels[b*512]] + endt[labels[b*512 + lidx]];
      lossp[b] = num - denom;
    }
  } else {
    // ---- Viterbi ----
    for (int t = 1; t < 512; t++) {
      float e = (l < 17) ? eb[t*17 + l] : 0.f;
      int mt = mask[b*512 + t];
      float best = -3e30f; int bi = 0;
      #pragma unroll
      for (int i = 0; i < 17; i++) {
        float v = __shfl(alpha, i) + tc[i];
        if (v > best) { best = v; bi = i; }   // first-max tie-break = np.argmax
      }
      float nxt = best + e;
      int bpv = (mt > 0) ? bi : l;
      if (l < 17) {
        bps[wv][t-1][l] = (unsigned char)bpv;
        if (mt > 0) alpha = nxt;
      }
    }
    __syncthreads();
    float a2 = (l < 17) ? (alpha + endt[l]) : -3e30f;
    float av[17];
    #pragma unroll
    for (int i = 0; i < 17; i++) av[i] = __shfl(a2, i);
    int bt = 0; float bv2 = av[0];
    #pragma unroll
    for (int i = 1; i < 17; i++) if (av[i] > bv2) { bv2 = av[i]; bt = i; }
    if (l == 0) outp[1 + b*512 + 511] = (float)bt;
    int tg = bt;
    for (int t = 510; t >= 0; --t) {
      tg = bps[wv][t][tg];
      if (l == 0) outp[1 + b*512 + t] = (float)tg;
    }
  }
}

// ---------------- K7: loss = -mean(num - denom), fp32 ----------------
__global__ __launch_bounds__(64) void k_final(const float* __restrict__ lossp,
                                              float* __restrict__ outp)
{
  int l = threadIdx.x;
  float v = lossp[l];
  #pragma unroll
  for (int o = 32; o > 0; o >>= 1) v += __shfl_xor(v, o);
  if (l == 0) outp[0] = -(v / 64.f);
}

// ---------------- host ----------------
extern "C" void kernel_launch(void* const* d_in, const int* in_sizes, int n_in,
                              void* d_out, int out_size, void* d_ws, size_t ws_size,
                              hipStream_t stream)
{
  (void)in_sizes; (void)n_in; (void)out_size; (void)ws_size;
  const int*   tok   = (const int*)d_in[0];
  const int*   ctok  = (const int*)d_in[1];
  const int*   labels= (const int*)d_in[2];
  const int*   amask = (const int*)d_in[3];
  const float* wemb  = (const float*)d_in[4];
  const float* cemb  = (const float*)d_in[5];
  const float* convw = (const float*)d_in[6];
  const float* convb = (const float*)d_in[7];
  const float* wihf  = (const float*)d_in[8];
  const float* whhf  = (const float*)d_in[9];
  const float* bfv   = (const float*)d_in[10];
  const float* wihb  = (const float*)d_in[11];
  const float* whhb  = (const float*)d_in[12];
  const float* bbv   = (const float*)d_in[13];
  const float* clsw  = (const float*)d_in[14];
  const float* clsb  = (const float*)d_in[15];
  const float* stt   = (const float*)d_in[16];
  const float* ent   = (const float*)d_in[17];
  const float* trn   = (const float*)d_in[18];

  // workspace layout (bytes): [cnt 512][hbuf 131072][z 20971520][gx 134217728]
  //                           [hs 33554432][emis 2228224][lossp 256]  ~191 MB
  char* ws = (char*)d_ws;
  int*      cnt  = (int*)ws;
  ushort_t* hbuf = (ushort_t*)(ws + 512);
  ushort_t* z    = (ushort_t*)(ws + 131584);
  ushort_t* gx   = (ushort_t*)(ws + 21103104);
  ushort_t* hs   = (ushort_t*)(ws + 155320832);
  float*    emis = (float*)(ws + 188875264);
  float*    lossp= (float*)(ws + 191103488);

  // zero sync counters + h double buffer (initial h = 0) — every launch
  hipMemsetAsync(ws, 0, 131584, stream);

  hipLaunchKernelGGL(k_embed,   dim3(B_*S_),       dim3(64),  0, stream,
                     tok, ctok, wemb, cemb, convw, convb, z);
  hipLaunchKernelGGL(k_gemm_gx, dim3(256, 32),     dim3(256), 0, stream,
                     z, wihf, wihb, gx);
  hipLaunchKernelGGL(k_lstm,    dim3(32),          dim3(256), 0, stream,
                     gx, whhf, whhb, bfv, bbv, hbuf, hs, cnt);
  hipLaunchKernelGGL(k_emis,    dim3((B_*S_ + 14)/15), dim3(256), 0, stream,
                     hs, clsw, clsb, emis);
  hipLaunchKernelGGL(k_crf,     dim3(32),          dim3(256), 0, stream,
                     emis, labels, amask, stt, ent, trn, lossp, (float*)d_out);
  hipLaunchKernelGGL(k_final,   dim3(1),           dim3(64),  0, stream,
                     lossp, (float*)d_out);
}